// Round 11
// baseline (114.444 us; speedup 1.0000x reference)
//
#include <hip/hip_runtime.h>

// TopKActivation: out = relu(x) masked to the row-wise top-k of relu(x).
// [16384 x 4096] fp32, k=64.
//
// R11 = R10 (one wave = one row, zero barriers) with the ambiguous-tie rank
// scan FIXED: R10 left a "P[q] |= t" corruption in the exclusive-prefix
// computation -> the one genuinely-tied row in the dataset came out wrong
// (absmax 2.2). Tie path rewritten as a single clean pass.
//
// STRUCTURE: lane l holds 64 elems (chunk j=0..15, cols j*256 + 4l..+3; every
// wave load = 1KiB contiguous). Ballot-compaction, radix select, tie handling,
// emit: all wave-internal (DS ops in-order within a wave -> no __syncthreads).
// 4 independent waves per 256-thread block; waves never interact.
//
// LESSON LEDGER:
//  R3: persistent blocks + prefetch -> 214us (lost TLP).
//  R4: launch_bounds(256,8) -> 302us (64-VGPR cap -> spills -> 660MB writes).
//  R5: NT stores -> 523MB writes, partial-line HBM write amplification.
//  R6: plain stores -> 127.5us.
//  R7: coalesced interleaved layout -> 100.9us (was 4x transactions).
//  R8: redundant all-wave select -> 112.5us (4x shared-pipe LDS traffic).
//  R9: ballot compaction + tie fast-path, 3 barriers -> 100.1us (flat).
//  R10: zero-barrier wave-per-row, tie-scan corrupted -> FAILED (1 tied row).
//
// Select: candidates > 1.5f (~274/row on N(0,1)) ballot-compacted into this
// wave's 512-slot LDS segment; 4x8-bit MSB radix on float bits (positive
// floats order as uints). Exact wave-internal fallback (histogram over all
// positives straight from regs) if cnt<k or cnt>512. Ties at T resolved
// stably (lowest column first) to match XLA top_k; fast path (total eq ==
// need, ~always) skips all rank bookkeeping.

constexpr int ROW_LEN = 4096;
constexpr int TPB     = 256;
constexpr int CAP     = 512;                    // per-wave candidate capacity
constexpr unsigned int KPRE_BITS = 0x3FC00000u; // bits of 1.5f

typedef float f32x4 __attribute__((ext_vector_type(4)));

__global__ __launch_bounds__(TPB, 4)
void topk_relu_kernel(const float* __restrict__ x, const int* __restrict__ kptr,
                      float* __restrict__ out, int rows)
{
    __shared__ unsigned int cand4[4][CAP];
    __shared__ alignas(16) int hist4[4][256];

    const int tid  = threadIdx.x;
    const int lane = tid & 63;
    const int wid  = tid >> 6;

    const int row = blockIdx.x * 4 + wid;
    if (row >= rows) return;

    int k = *kptr;
    if (k > ROW_LEN) k = ROW_LEN;

    // ---- load row: lane l, chunk j -> cols j*256 + 4l..+3 (1KiB per wave load) ----
    const float* __restrict__ xrow = x + (size_t)row * ROW_LEN;
    unsigned int key[64];
#pragma unroll
    for (int j = 0; j < 16; ++j) {
        f32x4 v = *(const f32x4*)(xrow + j * 256 + lane * 4);
#pragma unroll
        for (int c = 0; c < 4; ++c)
            key[4 * j + c] = __float_as_uint(fmaxf(v[c], 0.0f));
    }

    unsigned int* __restrict__ cand = &cand4[wid][0];
    int* __restrict__ hist = &hist4[wid][0];

    // ---- wave-internal ballot compaction of candidates > 1.5f ----
    int cnt = 0;
#pragma unroll
    for (int j = 0; j < 64; ++j) {
        const bool p = key[j] > KPRE_BITS;
        const unsigned long long mask = __ballot(p);
        const int prior = __builtin_amdgcn_mbcnt_hi(
            (unsigned int)(mask >> 32),
            __builtin_amdgcn_mbcnt_lo((unsigned int)mask, 0));
        const int idx = cnt + prior;
        if (p && idx < CAP) cand[idx] = key[j];
        cnt += (int)__popcll(mask); // wave-uniform
    }

    unsigned int T;
    int need;

    if (cnt >= k && cnt <= CAP) {
        // ---- fast select on compacted list (wave-internal, no barriers) ----
        unsigned int c[8];
#pragma unroll
        for (int i = 0; i < 8; ++i) {
            const int off = lane + 64 * i;
            c[i] = (off < cnt) ? cand[off] : 0u;
        }
        int kk = k;
        unsigned int prefix = 0;
#pragma unroll
        for (int p = 0; p < 4; ++p) {
            const int shift = 24 - 8 * p;
            ((int4*)hist)[lane] = make_int4(0, 0, 0, 0);
#pragma unroll
            for (int i = 0; i < 8; ++i) {
                const unsigned int ci = c[i];
                if (ci != 0u && (p == 0 || (ci >> (shift + 8)) == prefix))
                    atomicAdd(&hist[(ci >> shift) & 255u], 1);
            }
            const int4 h = ((const int4*)hist)[lane];
            const int h0 = h.x, h1 = h.y, h2 = h.z, h3 = h.w;
            const int lsum = h0 + h1 + h2 + h3;
            int suf = lsum; // inclusive suffix sum across lanes
#pragma unroll
            for (int d = 1; d < 64; d <<= 1) {
                int v = __shfl_down(suf, d);
                if (lane < 64 - d) suf += v;
            }
            const unsigned long long mm = __ballot(suf >= kk); // nonzero: cnt>=kk
            const int L = 63 - __clzll(mm);
            int dig = 0, kkn = 0;
            if (lane == L) {
                int cum = suf - lsum;
                const int hh[4] = {h0, h1, h2, h3};
#pragma unroll
                for (int b = 3; b >= 0; --b) {
                    if (cum + hh[b] >= kk) { dig = lane * 4 + b; kkn = kk - cum; break; }
                    cum += hh[b];
                }
            }
            dig = __shfl(dig, L);
            kk  = __shfl(kkn, L);
            prefix = (prefix << 8) | (unsigned int)dig;
        }
        T = prefix;
        need = kk;
    } else {
        // ---- exact fallback: histogram over all positives straight from regs ----
        int kk = k;
        unsigned int prefix = 0;
        bool t0 = false;
        for (int p = 0; p < 4 && !t0; ++p) {
            const int shift = 24 - 8 * p;
            ((int4*)hist)[lane] = make_int4(0, 0, 0, 0);
#pragma unroll
            for (int j = 0; j < 64; ++j) {
                const unsigned int kj = key[j];
                if (kj != 0u && (p == 0 || (kj >> (shift + 8)) == prefix))
                    atomicAdd(&hist[(kj >> shift) & 255u], 1);
            }
            const int4 h = ((const int4*)hist)[lane];
            const int h0 = h.x, h1 = h.y, h2 = h.z, h3 = h.w;
            const int lsum = h0 + h1 + h2 + h3;
            int suf = lsum;
#pragma unroll
            for (int d = 1; d < 64; d <<= 1) {
                int v = __shfl_down(suf, d);
                if (lane < 64 - d) suf += v;
            }
            const unsigned long long mm = __ballot(suf >= kk);
            if (mm == 0ull) {
                t0 = true; // fewer than kk positives remain -> threshold 0
            } else {
                const int L = 63 - __clzll(mm);
                int dig = 0, kkn = 0;
                if (lane == L) {
                    int cum = suf - lsum;
                    const int hh[4] = {h0, h1, h2, h3};
#pragma unroll
                    for (int b = 3; b >= 0; --b) {
                        if (cum + hh[b] >= kk) { dig = lane * 4 + b; kkn = kk - cum; break; }
                        cum += hh[b];
                    }
                }
                dig = __shfl(dig, L);
                kk  = __shfl(kkn, L);
                prefix = (prefix << 8) | (unsigned int)dig;
            }
        }
        if (t0) { T = 0u; need = 0; }
        else    { T = prefix; need = kk; }
    }

    // ---- tie disambiguation (wave-internal) ----
    int eqc = 0;
#pragma unroll
    for (int j = 0; j < 64; ++j) eqc += (key[j] == T) ? 1 : 0;
    int tot = eqc;
#pragma unroll
    for (int d = 1; d < 64; d <<= 1) tot += __shfl_xor(tot, d); // all-lanes total

    float* __restrict__ orow = out + (size_t)row * ROW_LEN;

    if (tot == need) {
        // ---- emit fast path: all ==T kept, no rank bookkeeping ----
#pragma unroll
        for (int j = 0; j < 16; ++j) {
            f32x4 v;
#pragma unroll
            for (int c2 = 0; c2 < 4; ++c2) {
                const unsigned int kj = key[4 * j + c2];
                v[c2] = (kj >= T && T != 0u) ? __uint_as_float(kj) : 0.0f;
            }
            *(f32x4*)(orow + j * 256 + lane * 4) = v;
        }
    } else {
        // ---- rare: ambiguous tie at T. Stable rank, column order ==
        //      lexicographic (j, lane, c). One clean pass per 4-chunk group:
        //      pack eq-counts 4x16-bit -> u64 inclusive scan -> exclusive
        //      prefix (per lane) + wave totals (lane 63). ----
        unsigned long long exclp[4]; // exclusive prefix, 4x16-bit fields
        int totj[16];                // per-chunk wave totals
#pragma unroll
        for (int q = 0; q < 4; ++q) {
            unsigned long long pk = 0ull;
#pragma unroll
            for (int jj = 0; jj < 4; ++jj) {
                const int j = 4 * q + jj;
                int e = 0;
#pragma unroll
                for (int c = 0; c < 4; ++c) e += (key[4 * j + c] == T) ? 1 : 0;
                pk |= (unsigned long long)e << (16 * jj);
            }
            unsigned long long incp = pk;
#pragma unroll
            for (int d = 1; d < 64; d <<= 1) {
                unsigned long long v = __shfl_up(incp, d);
                if (lane >= d) incp += v;
            }
            exclp[q] = incp - pk;
            const unsigned long long t = __shfl(incp, 63);
#pragma unroll
            for (int jj = 0; jj < 4; ++jj)
                totj[4 * q + jj] = (int)((t >> (16 * jj)) & 0xFFFFull);
        }
        int S[16]; // start rank of each chunk j
        S[0] = 0;
#pragma unroll
        for (int j = 1; j < 16; ++j) S[j] = S[j - 1] + totj[j - 1];

#pragma unroll
        for (int j = 0; j < 16; ++j) {
            const int q = j >> 2, jj = j & 3;
            int rr = S[j] + (int)((exclp[q] >> (16 * jj)) & 0xFFFFull);
            f32x4 v;
#pragma unroll
            for (int c2 = 0; c2 < 4; ++c2) {
                const unsigned int kj = key[4 * j + c2];
                const bool eq = (kj == T);
                const bool keep = (kj > T) || (eq && rr < need);
                v[c2] = keep ? __uint_as_float(kj) : 0.0f;
                rr += eq ? 1 : 0;
            }
            *(f32x4*)(orow + j * 256 + lane * 4) = v;
        }
    }
}

extern "C" void kernel_launch(void* const* d_in, const int* in_sizes, int n_in,
                              void* d_out, int out_size, void* d_ws, size_t ws_size,
                              hipStream_t stream)
{
    const float* x    = (const float*)d_in[0];
    const int*   kptr = (const int*)d_in[1];
    float*       out  = (float*)d_out;
    const int rows = in_sizes[0] / ROW_LEN;
    const int nb = (rows + 3) / 4;
    topk_relu_kernel<<<nb, TPB, 0, stream>>>(x, kptr, out, rows);
}

// Round 12
// 101.168 us; speedup vs baseline: 1.1312x; 1.1312x over previous
//
#include <hip/hip_runtime.h>

// TopKActivation: out = relu(x) masked to the row-wise top-k of relu(x).
// [16384 x 4096] fp32, k=64. One 256-thread block per row, interleaved
// coalesced layout (thread t, chunk j -> cols j*1024 + 4t..+3).
//
// LESSON LEDGER:
//  R3:  persistent blocks + prefetch -> 214us (lost TLP).
//  R4:  launch_bounds(256,8) -> 302us (write amplification).
//  R5:  NT stores -> 523MB writes (partial-line HBM write amplification).
//  R6:  plain stores -> 127.5us.
//  R7:  coalesced interleaved layout -> 100.9us (was 4x transactions).
//  R8:  redundant all-wave select -> 112.5us (4x shared-pipe LDS traffic).
//  R9:  ballot compaction + tie fast-path, 3 barriers -> 100.1us.
//  R10: zero-barrier wave-per-row, corrupted tie scan -> FAILED.
//  R11: wave-per-row fixed -> 114.4us: 64-elem/lane VGPR pressure + 64 serial
//       compaction ballots beat the saved barriers. R9 structure wins.
//  R12 (this): R9 + (a) 24-bit offset keys: candidates>1.5 stored as
//       key-0x3FC00000 -> top byte always 0 -> radix select is 3 passes, and
//       the old pass-0 (512 atomics into ~2 bins, worst-case same-address
//       serialization) disappears. Exact guard: any element >= 6.0 -> fallback.
//       (b) tie ambiguity decided inside the select (final-pass hist[dig] ==
//       multiplicity of T) -> block eq-reduction + barrier B3 deleted.
//       Fast path: 2 barriers.
//
// Ties at T resolved stably (lowest column first) to match XLA top_k.

constexpr int ROW_LEN = 4096;
constexpr int TPB     = 256;
constexpr int SEG     = 128;   // per-wave candidate capacity
constexpr unsigned int KPRE_BITS = 0x3FC00000u; // bits of 1.5f
constexpr unsigned int KMAX_BITS = 0x40C00000u; // bits of 6.0f (24-bit guard)

typedef float f32x4 __attribute__((ext_vector_type(4)));

__global__ __launch_bounds__(TPB, 4)
void topk_relu_kernel(const float* __restrict__ x, const int* __restrict__ kptr,
                      float* __restrict__ out, int rows)
{
    __shared__ alignas(16) int hist[256];
    __shared__ unsigned int cand[4 * SEG];  // 4 segments of 128 (24-bit offset keys)
    __shared__ int scnt[4];
    __shared__ unsigned int wmax[4];
    __shared__ unsigned int selT;
    __shared__ int selNeed, selAmb;
    __shared__ unsigned long long wtot64[4];
    __shared__ int sel_digit, sel_kk, sel_eq, sel_flag;

    const int row = blockIdx.x;
    if (row >= rows) return;
    const int tid  = threadIdx.x;
    const int lane = tid & 63;
    const int wid  = tid >> 6;

    int k = *kptr;
    if (k > ROW_LEN) k = ROW_LEN;

    // ---- load row, interleaved coalesced: thread t chunk j -> cols j*1024+4t..+3 ----
    const float* __restrict__ xrow = x + (size_t)row * ROW_LEN;
    unsigned int key[16];
#pragma unroll
    for (int j = 0; j < 4; ++j) {
        f32x4 v = *(const f32x4*)(xrow + j * 1024 + tid * 4);
#pragma unroll
        for (int c = 0; c < 4; ++c)
            key[4 * j + c] = __float_as_uint(fmaxf(v[c], 0.0f));
    }

    // ---- per-wave ballot compaction of candidates > 1.5f (stored as key-1.5bits)
    //      + wave max (for the 24-bit guard) ----
    unsigned int mx = 0u;
#pragma unroll
    for (int j = 0; j < 16; ++j) mx = key[j] > mx ? key[j] : mx;
#pragma unroll
    for (int d = 1; d < 64; d <<= 1) {
        unsigned int o = __shfl_xor(mx, d);
        mx = o > mx ? o : mx;
    }
    int base = 0;
#pragma unroll
    for (int j = 0; j < 16; ++j) {
        const bool p = key[j] > KPRE_BITS;
        const unsigned long long mask = __ballot(p);
        const int prior = __builtin_amdgcn_mbcnt_hi(
            (unsigned int)(mask >> 32),
            __builtin_amdgcn_mbcnt_lo((unsigned int)mask, 0));
        const int idx = base + prior;
        if (p && idx < SEG) cand[(wid << 7) + idx] = key[j] - KPRE_BITS;
        base += (int)__popcll(mask);
    }
    if (lane == 0) { scnt[wid] = base; wmax[wid] = mx; }
    __syncthreads(); // B1: segments + counts + maxes ready

    const int c0 = scnt[0], c1 = scnt[1], c2 = scnt[2], c3 = scnt[3];
    const int cnt = c0 + c1 + c2 + c3;
    const bool segok = (c0 <= SEG) & (c1 <= SEG) & (c2 <= SEG) & (c3 <= SEG);
    unsigned int bmax = wmax[0];
    bmax = wmax[1] > bmax ? wmax[1] : bmax;
    bmax = wmax[2] > bmax ? wmax[2] : bmax;
    bmax = wmax[3] > bmax ? wmax[3] : bmax;

    unsigned int T;
    int need, amb;

    if (cnt >= k && segok && bmax < KMAX_BITS) {
        // ---- fast select: wave 0 only, 3x8-bit radix on 24-bit offset keys ----
        if (wid == 0) {
            const int sc[4] = {c0, c1, c2, c3};
            unsigned int c[8];
#pragma unroll
            for (int i = 0; i < 8; ++i) {
                const int s   = i >> 1;
                const int off = lane + 64 * (i & 1);
                c[i] = (off < sc[s]) ? cand[(s << 7) + off] : 0u; // 0 = invalid (cands >= 1)
            }
            int kk = k;
            int eqv = 0;
            unsigned int prefix = 0;
#pragma unroll
            for (int p = 0; p < 3; ++p) {
                const int shift = 16 - 8 * p;
                ((int4*)hist)[lane] = make_int4(0, 0, 0, 0);
#pragma unroll
                for (int i = 0; i < 8; ++i) {
                    const unsigned int ci = c[i];
                    if (ci != 0u && (p == 0 || (ci >> (shift + 8)) == prefix))
                        atomicAdd(&hist[(ci >> shift) & 255u], 1);
                }
                const int4 h = ((const int4*)hist)[lane];
                const int h0 = h.x, h1 = h.y, h2 = h.z, h3 = h.w;
                const int lsum = h0 + h1 + h2 + h3;
                int suf = lsum; // inclusive suffix sum across lanes
#pragma unroll
                for (int d = 1; d < 64; d <<= 1) {
                    int v = __shfl_down(suf, d);
                    if (lane < 64 - d) suf += v;
                }
                const unsigned long long mm = __ballot(suf >= kk); // nonzero: cnt>=kk
                const int L = 63 - __clzll(mm);
                int dig = 0, kkn = 0, eqn = 0;
                if (lane == L) {
                    int cum = suf - lsum;
                    const int hh[4] = {h0, h1, h2, h3};
#pragma unroll
                    for (int b = 3; b >= 0; --b) {
                        if (cum + hh[b] >= kk) { dig = lane * 4 + b; kkn = kk - cum; eqn = hh[b]; break; }
                        cum += hh[b];
                    }
                }
                dig = __shfl(dig, L);
                kk  = __shfl(kkn, L);
                eqv = __shfl(eqn, L);
                prefix = (prefix << 8) | (unsigned int)dig;
            }
            if (lane == 0) {
                selT    = prefix + KPRE_BITS; // back to full float bits
                selNeed = kk;
                selAmb  = (eqv != kk); // final-pass bin count == multiplicity of T
            }
        }
        __syncthreads(); // B2: T/need/amb ready
        T    = selT;
        need = selNeed;
        amb  = selAmb;
    } else {
        // ---- exact fallback: full-block 4-pass histogram over all positives ----
        int kk = k;
        unsigned int prefix = 0;
        int t0 = 0;
        for (int p = 0; p < 4; ++p) {
            const int shift = 24 - 8 * p;
            hist[tid] = 0;
            if (tid == 0) sel_flag = 0;
            __syncthreads();
#pragma unroll
            for (int j = 0; j < 16; ++j) {
                const unsigned int kj = key[j];
                if (kj != 0u && (p == 0 || (kj >> (shift + 8)) == prefix))
                    atomicAdd(&hist[(kj >> shift) & 255u], 1);
            }
            __syncthreads();
            if (tid < 64) {
                const int b0 = tid * 4;
                const int h0 = hist[b0 + 0], h1 = hist[b0 + 1];
                const int h2 = hist[b0 + 2], h3 = hist[b0 + 3];
                const int lsum = h0 + h1 + h2 + h3;
                int suf = lsum;
#pragma unroll
                for (int d = 1; d < 64; d <<= 1) {
                    int v = __shfl_down(suf, d);
                    if (lane < 64 - d) suf += v;
                }
                const unsigned long long mm = __ballot(suf >= kk);
                if (mm == 0ull) {
                    if (lane == 0) sel_flag = 1;
                } else {
                    const int L = 63 - __clzll(mm);
                    if (lane == L) {
                        int cum = suf - lsum;
                        const int hh[4] = {h0, h1, h2, h3};
#pragma unroll
                        for (int b = 3; b >= 0; --b) {
                            if (cum + hh[b] >= kk) {
                                sel_digit = b0 + b; sel_kk = kk - cum; sel_eq = hh[b]; break;
                            }
                            cum += hh[b];
                        }
                    }
                }
            }
            __syncthreads();
            if (sel_flag) { t0 = 1; break; }
            prefix = (prefix << 8) | (unsigned int)sel_digit;
            kk = sel_kk;
            __syncthreads(); // protect sel_* from next pass's re-init
        }
        if (t0) { T = 0u; need = 0; amb = 1; } // rank path yields keep = (kj > 0)
        else    { T = prefix; need = kk; amb = (sel_eq != kk); }
    }

    float* __restrict__ orow = out + (size_t)row * ROW_LEN;

    if (!amb) {
        // ---- emit fast path: all ==T kept, no rank bookkeeping ----
#pragma unroll
        for (int j = 0; j < 4; ++j) {
            f32x4 v;
#pragma unroll
            for (int c2 = 0; c2 < 4; ++c2) {
                const unsigned int kj = key[4 * j + c2];
                v[c2] = (kj >= T && T != 0u) ? __uint_as_float(kj) : 0.0f;
            }
            *(f32x4*)(orow + j * 1024 + tid * 4) = v;
        }
    } else {
        // ---- rare: ambiguous tie at T (or t0 fallback). Stable rank in column
        //      order == lexicographic (j, tid, c). Packed 4x16-bit block scan. ----
        unsigned long long packed = 0ull;
#pragma unroll
        for (int j = 0; j < 4; ++j) {
            int e = 0;
#pragma unroll
            for (int c = 0; c < 4; ++c) e += (key[4 * j + c] == T) ? 1 : 0;
            packed |= (unsigned long long)e << (16 * j);
        }
        unsigned long long incp = packed;
#pragma unroll
        for (int d = 1; d < 64; d <<= 1) {
            unsigned long long v = __shfl_up(incp, d);
            if (lane >= d) incp += v;
        }
        if (lane == 63) wtot64[wid] = incp;
        __syncthreads(); // rare path only
        unsigned long long b64 = 0ull;
        for (int w = 0; w < wid; ++w) b64 += wtot64[w];
        const unsigned long long exclp = b64 + incp - packed;
        const unsigned long long t64 = wtot64[0] + wtot64[1] + wtot64[2] + wtot64[3];
        int S[4];
        S[0] = 0;
        S[1] = (int)(t64 & 0xFFFFull);
        S[2] = S[1] + (int)((t64 >> 16) & 0xFFFFull);
        S[3] = S[2] + (int)((t64 >> 32) & 0xFFFFull);
#pragma unroll
        for (int j = 0; j < 4; ++j) {
            int rr = S[j] + (int)((exclp >> (16 * j)) & 0xFFFFull);
            f32x4 v;
#pragma unroll
            for (int c2 = 0; c2 < 4; ++c2) {
                const unsigned int kj = key[4 * j + c2];
                const bool eq = (kj == T);
                const bool keep = (kj > T) || (eq && rr < need);
                v[c2] = keep ? __uint_as_float(kj) : 0.0f;
                rr += eq ? 1 : 0;
            }
            *(f32x4*)(orow + j * 1024 + tid * 4) = v;
        }
    }
}

extern "C" void kernel_launch(void* const* d_in, const int* in_sizes, int n_in,
                              void* d_out, int out_size, void* d_ws, size_t ws_size,
                              hipStream_t stream)
{
    const float* x    = (const float*)d_in[0];
    const int*   kptr = (const int*)d_in[1];
    float*       out  = (float*)d_out;
    const int rows = in_sizes[0] / ROW_LEN;
    topk_relu_kernel<<<rows, TPB, 0, stream>>>(x, kptr, out, rows);
}